// Round 9
// baseline (225.769 us; speedup 1.0000x reference)
//
#include <hip/hip_runtime.h>

#define N_NODES 100000
#define N_EDGES 800000
#define N_PAIRS 500000
#define SCAN_BLK 1024
#define N_SBLKS ((N_NODES + SCAN_BLK - 1) / SCAN_BLK)   // 98

#define T_TILE  4096
#define N_TILES ((N_EDGES + T_TILE - 1) / T_TILE)       // 196
#define N_BKT   256
#define NPB     391                                     // nodes per bucket
#define BCAP    4096                                    // reorder staging capacity

typedef _Float16 half4v __attribute__((ext_vector_type(4)));
typedef _Float16 half8v __attribute__((ext_vector_type(8)));
typedef float    f32x4  __attribute__((ext_vector_type(4)));

// ---------------------------------------------------------------------------
// Pre-transpose + fp16-convert weights: Wt[m][k] = (half)W[k][m].  Tiny.
// ---------------------------------------------------------------------------
__global__ __launch_bounds__(256) void transpose_w(const float* __restrict__ W1,
                                                   const float* __restrict__ W2,
                                                   _Float16* __restrict__ Wt1,
                                                   _Float16* __restrict__ Wt2) {
    for (int i = threadIdx.x; i < 128 * 128; i += 256) {
        const int k = i >> 7, m = i & 127;
        Wt1[m * 128 + k] = (_Float16)W1[i];
    }
    for (int i = threadIdx.x; i < 128 * 64; i += 256) {
        const int k = i >> 6, m = i & 63;
        Wt2[m * 128 + k] = (_Float16)W2[i];
    }
}

// ---------------------------------------------------------------------------
// XOR-16B LDS swizzle: byte ^= (row&7)<<4 -> fragment reads <=2-way (free).
// v_mfma_f32_16x16x16_f16: A: lane l holds A[l%16][4*(l/16)+i];
//   B: B[4*(l/16)+i][l%16]; D: D[4*(l/16)+i][l%16].
// ---------------------------------------------------------------------------
__device__ __forceinline__ int swz(int byte_off, int row) {
    return byte_off ^ ((row & 7) << 4);
}

template<int M, bool A_IS_F32>
__global__ __launch_bounds__(256) void gemm_mfma(const void* __restrict__ Ap,
                                                 const _Float16* __restrict__ Wt,
                                                 _Float16* __restrict__ C, int nRows) {
    constexpr int K  = 128;
    constexpr int CT = M / 16;
    __shared__ _Float16 Alds[64 * K];
    __shared__ _Float16 Wlds[M * K];

    const int rb = blockIdx.x * 64;

    if (A_IS_F32) {
        const float* A = (const float*)Ap;
        for (int idx = threadIdx.x; idx < 64 * (K / 4); idx += 256) {
            const int row = idx >> 5, c4 = idx & 31;
            const int rg = (rb + row < nRows) ? rb + row : nRows - 1;
            const float4 a = *(const float4*)&A[(long)rg * K + c4 * 4];
            half4v h = { (_Float16)a.x, (_Float16)a.y, (_Float16)a.z, (_Float16)a.w };
            *(half4v*)((char*)Alds + swz(row * 256 + c4 * 8, row)) = h;
        }
    } else {
        const _Float16* A = (const _Float16*)Ap;
        for (int idx = threadIdx.x; idx < 64 * (K / 8); idx += 256) {
            const int row = idx >> 4, seg = idx & 15;
            const int rg = (rb + row < nRows) ? rb + row : nRows - 1;
            const half8v h = *(const half8v*)&A[(long)rg * K + seg * 8];
            *(half8v*)((char*)Alds + swz(row * 256 + seg * 16, row)) = h;
        }
    }
    for (int idx = threadIdx.x; idx < M * (K / 8); idx += 256) {
        const int col = idx >> 4, seg = idx & 15;
        const half8v h = *(const half8v*)&Wt[col * K + seg * 8];
        *(half8v*)((char*)Wlds + swz(col * 256 + seg * 16, col)) = h;
    }
    __syncthreads();

    const int l  = threadIdx.x & 63;
    const int w  = threadIdx.x >> 6;
    const int lr = l & 15;
    const int lg = l >> 4;

    f32x4 acc[CT];
    #pragma unroll
    for (int ct = 0; ct < CT; ++ct) acc[ct] = (f32x4){0.f, 0.f, 0.f, 0.f};

    #pragma unroll
    for (int ks = 0; ks < K / 16; ++ks) {
        const int kb   = ks * 32 + lg * 8;
        const int arow = w * 16 + lr;
        const half4v af = *(const half4v*)((const char*)Alds + swz(arow * 256 + kb, arow));
        #pragma unroll
        for (int ct = 0; ct < CT; ++ct) {
            const int col = ct * 16 + lr;
            const half4v bf = *(const half4v*)((const char*)Wlds + swz(col * 256 + kb, col));
            acc[ct] = __builtin_amdgcn_mfma_f32_16x16x16f16(af, bf, acc[ct], 0, 0, 0);
        }
    }

    #pragma unroll
    for (int ct = 0; ct < CT; ++ct) {
        const int col = ct * 16 + lr;
        #pragma unroll
        for (int j = 0; j < 4; ++j) {
            const int row = rb + w * 16 + lg * 4 + j;
            if (row < nRows) C[(long)row * M + col] = (_Float16)acc[ct][j];
        }
    }
}

// ---------------------------------------------------------------------------
// FUSED: g2[64 rows, 64] = relu(A_sp @ g1)[tile] @ Wt2^T.
// Phase 1 (spmm): 16 lanes per row gather+accumulate, relu, write half8 into
// swizzled A-LDS tile.  Phase 2: identical MFMA loop as gemm_mfma<64,false>.
// agg1 never touches HBM.
// ---------------------------------------------------------------------------
__global__ __launch_bounds__(256) void spmm_gemm_fused(const int* __restrict__ rowptr,
                                                       const long long* __restrict__ epack,
                                                       const _Float16* __restrict__ g,
                                                       const _Float16* __restrict__ Wt2,
                                                       _Float16* __restrict__ g2, int nRows) {
    constexpr int K = 128, M = 64, CT = M / 16;
    __shared__ _Float16 Alds[64 * K];
    __shared__ _Float16 Wlds[M * K];

    const int rb = blockIdx.x * 64;

    // stage Wt2
    for (int idx = threadIdx.x; idx < M * (K / 8); idx += 256) {
        const int col = idx >> 4, seg = idx & 15;
        const half8v h = *(const half8v*)&Wt2[col * K + seg * 8];
        *(half8v*)((char*)Wlds + swz(col * 256 + seg * 16, col)) = h;
    }

    // phase 1: spmm into Alds
    const int li = threadIdx.x & 15;        // 16 lanes per row, 8 dims each
    const int rg = threadIdx.x >> 4;        // 16 row-groups
    #pragma unroll
    for (int s = 0; s < 4; ++s) {
        const int lrow = s * 16 + rg;
        const int r  = rb + lrow;
        const int rc = (r < nRows) ? r : nRows - 1;
        const int lo = rowptr[rc], hi = rowptr[rc + 1];
        float acc[8] = {0.f, 0.f, 0.f, 0.f, 0.f, 0.f, 0.f, 0.f};
        for (int e = lo; e < hi; ++e) {
            const long long pk = epack[e];
            const int   c = (int)pk;
            const float v = __int_as_float((int)(pk >> 32));
            const half8v m = *(const half8v*)&g[(long)c * K + li * 8];
            #pragma unroll
            for (int j = 0; j < 8; ++j) acc[j] += v * (float)m[j];
        }
        half8v h;
        #pragma unroll
        for (int j = 0; j < 8; ++j) h[j] = (_Float16)fmaxf(acc[j], 0.f);
        *(half8v*)((char*)Alds + swz(lrow * 256 + li * 16, lrow)) = h;
    }
    __syncthreads();

    // phase 2: MFMA
    const int l  = threadIdx.x & 63;
    const int w  = threadIdx.x >> 6;
    const int lr = l & 15;
    const int lg = l >> 4;

    f32x4 acc[CT];
    #pragma unroll
    for (int ct = 0; ct < CT; ++ct) acc[ct] = (f32x4){0.f, 0.f, 0.f, 0.f};

    #pragma unroll
    for (int ks = 0; ks < K / 16; ++ks) {
        const int kb   = ks * 32 + lg * 8;
        const int arow = w * 16 + lr;
        const half4v af = *(const half4v*)((const char*)Alds + swz(arow * 256 + kb, arow));
        #pragma unroll
        for (int ct = 0; ct < CT; ++ct) {
            const int col = ct * 16 + lr;
            const half4v bf = *(const half4v*)((const char*)Wlds + swz(col * 256 + kb, col));
            acc[ct] = __builtin_amdgcn_mfma_f32_16x16x16f16(af, bf, acc[ct], 0, 0, 0);
        }
    }

    #pragma unroll
    for (int ct = 0; ct < CT; ++ct) {
        const int col = ct * 16 + lr;
        #pragma unroll
        for (int j = 0; j < 4; ++j) {
            const int row = rb + w * 16 + lg * 4 + j;
            if (row < nRows) g2[(long)row * M + col] = (_Float16)acc[ct][j];
        }
    }
}

// ---------------------------------------------------------------------------
// rowptr build: fused per-node + per-(bucket,tile) histogram -> 3-phase scan
// ---------------------------------------------------------------------------
__global__ __launch_bounds__(256) void hist_both(const int* __restrict__ erows,
                                                 int* __restrict__ deg,
                                                 int* __restrict__ hist) {
    __shared__ int cnt[N_BKT];
    cnt[threadIdx.x] = 0;
    __syncthreads();
    const int e0 = blockIdx.x * T_TILE;
    const int e1 = min(e0 + T_TILE, N_EDGES);
    for (int e = e0 + threadIdx.x; e < e1; e += 256) {
        const int r = erows[e];
        atomicAdd(&deg[r], 1);
        atomicAdd(&cnt[r / NPB], 1);
    }
    __syncthreads();
    hist[threadIdx.x * N_TILES + blockIdx.x] = cnt[threadIdx.x];
}

__global__ __launch_bounds__(SCAN_BLK) void scan_phase1(const int* __restrict__ deg,
                                                        int* __restrict__ bsum) {
    const int i = blockIdx.x * SCAN_BLK + threadIdx.x;
    int v = (i < N_NODES) ? deg[i] : 0;
    #pragma unroll
    for (int off = 1; off < 64; off <<= 1) v += __shfl_xor(v, off);
    __shared__ int ws[SCAN_BLK / 64];
    if ((threadIdx.x & 63) == 0) ws[threadIdx.x >> 6] = v;
    __syncthreads();
    if (threadIdx.x < SCAN_BLK / 64) {
        int s = ws[threadIdx.x];
        #pragma unroll
        for (int off = 1; off < SCAN_BLK / 64; off <<= 1) s += __shfl_xor(s, off);
        if (threadIdx.x == 0) bsum[blockIdx.x] = s;
    }
}

__global__ __launch_bounds__(128) void scan_phase2(const int* __restrict__ bsum,
                                                   int* __restrict__ boff,
                                                   int* __restrict__ rowptr) {
    __shared__ int lds[128];
    const int t = threadIdx.x;
    const int v = (t < N_SBLKS) ? bsum[t] : 0;
    lds[t] = v;
    __syncthreads();
    for (int off = 1; off < 128; off <<= 1) {
        int u = (t >= off) ? lds[t - off] : 0;
        __syncthreads();
        lds[t] += u;
        __syncthreads();
    }
    if (t < N_SBLKS) boff[t] = lds[t] - v;
    if (t == N_SBLKS - 1) rowptr[N_NODES] = lds[t];
}

__global__ __launch_bounds__(SCAN_BLK) void scan_phase3(const int* __restrict__ deg,
                                                        const int* __restrict__ boff,
                                                        int* __restrict__ rowptr) {
    const int i    = blockIdx.x * SCAN_BLK + threadIdx.x;
    const int lane = threadIdx.x & 63;
    const int wid  = threadIdx.x >> 6;
    const int v = (i < N_NODES) ? deg[i] : 0;
    int s = v;
    #pragma unroll
    for (int off = 1; off < 64; off <<= 1) {
        int u = __shfl_up(s, off);
        if (lane >= off) s += u;
    }
    __shared__ int wsum[SCAN_BLK / 64];
    __shared__ int woff[SCAN_BLK / 64];
    if (lane == 63) wsum[wid] = s;
    __syncthreads();
    if (threadIdx.x < SCAN_BLK / 64) {
        const int t0 = wsum[threadIdx.x];
        int q = t0;
        #pragma unroll
        for (int off = 1; off < SCAN_BLK / 64; off <<= 1) {
            int u = __shfl_up(q, off);
            if ((int)threadIdx.x >= off) q += u;
        }
        woff[threadIdx.x] = q - t0;
    }
    __syncthreads();
    const int ex = (s - v) + woff[wid] + boff[blockIdx.x];
    if (i < N_NODES) rowptr[i] = ex;
}

// ---------------------------------------------------------------------------
// Edge partition into CSR order (2-level; see R7 notes).
// tmp record: [val:32][lrow:9][col:17].  Final: [val:32][col:32].
// ---------------------------------------------------------------------------
__global__ __launch_bounds__(256) void bucket_scan(const int* __restrict__ hist,
                                                   const int* __restrict__ rowptr,
                                                   int* __restrict__ off) {
    __shared__ int lds[256];
    const int b = blockIdx.x;
    const int t = threadIdx.x;
    const int v = (t < N_TILES) ? hist[b * N_TILES + t] : 0;
    lds[t] = v;
    __syncthreads();
    for (int o = 1; o < 256; o <<= 1) {
        int u = (t >= o) ? lds[t - o] : 0;
        __syncthreads();
        lds[t] += u;
        __syncthreads();
    }
    if (t < N_TILES) off[b * N_TILES + t] = rowptr[b * NPB] + lds[t] - v;
}

__global__ __launch_bounds__(256) void partition(const int* __restrict__ erows,
                                                 const int* __restrict__ ecols,
                                                 const float* __restrict__ evals,
                                                 const int* __restrict__ off,
                                                 unsigned long long* __restrict__ etmp) {
    __shared__ int cur[N_BKT];
    cur[threadIdx.x] = off[threadIdx.x * N_TILES + blockIdx.x];
    __syncthreads();
    const int e0 = blockIdx.x * T_TILE;
    const int e1 = min(e0 + T_TILE, N_EDGES);
    for (int e = e0 + threadIdx.x; e < e1; e += 256) {
        const int r = erows[e];
        const int b = r / NPB;
        const int lrow = r - b * NPB;
        const int p = atomicAdd(&cur[b], 1);
        etmp[p] = ((unsigned long long)(unsigned)__float_as_int(evals[e]) << 32)
                | ((unsigned)lrow << 17) | (unsigned)ecols[e];
    }
}

__global__ __launch_bounds__(256) void bucket_reorder(const int* __restrict__ rowptr,
                                                      const unsigned long long* __restrict__ etmp,
                                                      unsigned long long* __restrict__ epack) {
    __shared__ int lcur[NPB];
    __shared__ unsigned long long stg[BCAP];
    const int b    = blockIdx.x;
    const int lo   = b * NPB;
    const int hiN  = min(lo + NPB, N_NODES);
    const int base = rowptr[lo];
    const int cnt  = rowptr[hiN] - base;
    for (int j = threadIdx.x; j < hiN - lo; j += 256)
        lcur[j] = rowptr[lo + j] - base;
    __syncthreads();
    for (int i = threadIdx.x; i < cnt; i += 256) {
        const unsigned long long p = etmp[base + i];
        const int lrow = (int)((p >> 17) & 0x1FF);
        const int pos  = atomicAdd(&lcur[lrow], 1);
        const unsigned long long rec = (p & 0xFFFFFFFF00000000ULL) | (p & 0x1FFFFULL);
        if (pos < BCAP) stg[pos] = rec;
        else epack[base + pos] = rec;   // safety fallback (statistically never)
    }
    __syncthreads();
    const int n = min(cnt, BCAP);
    for (int i = threadIdx.x; i < n; i += 256)
        epack[base + i] = stg[i];
}

// ---------------------------------------------------------------------------
// CSR SpMM (gather, fp16 data, f32 accumulate): agg[r] = sum vals*g[cols]
// ---------------------------------------------------------------------------
template<int D, bool RELU>
__global__ __launch_bounds__(256) void spmm_csr_h(const int* __restrict__ rowptr,
                                                  const long long* __restrict__ epack,
                                                  const _Float16* __restrict__ g,
                                                  _Float16* __restrict__ agg, int nRows) {
    constexpr int LPR = D / 8;
    constexpr int RPB = 256 / LPR;
    const int r  = blockIdx.x * RPB + threadIdx.x / LPR;
    const int li = threadIdx.x % LPR;
    if (r >= nRows) return;
    const int lo = rowptr[r], hi = rowptr[r + 1];
    float acc[8] = {0.f, 0.f, 0.f, 0.f, 0.f, 0.f, 0.f, 0.f};
    #pragma unroll 2
    for (int e = lo; e < hi; ++e) {
        const long long pk = epack[e];
        const int   c = (int)pk;
        const float v = __int_as_float((int)(pk >> 32));
        const half8v m = *(const half8v*)&g[(long)c * D + li * 8];
        #pragma unroll
        for (int j = 0; j < 8; ++j) acc[j] += v * (float)m[j];
    }
    half8v o;
    #pragma unroll
    for (int j = 0; j < 8; ++j) {
        float a = RELU ? fmaxf(acc[j], 0.f) : acc[j];
        o[j] = (_Float16)a;
    }
    *(half8v*)&agg[(long)r * D + li * 8] = o;
}

// ---------------------------------------------------------------------------
// Decode: out[p] = dot(h2[pairs.x], h2[pairs.y]) over 64 f16 dims, f32 acc.
// ---------------------------------------------------------------------------
__global__ __launch_bounds__(256) void decode_dot(const _Float16* __restrict__ h2,
                                                  const int2* __restrict__ pairs,
                                                  float* __restrict__ out, int nPairs) {
    const int tid  = blockIdx.x * 256 + threadIdx.x;
    const int p    = tid >> 3;
    const int lane = tid & 7;
    if (p >= nPairs) return;
    const int2 pr = pairs[p];
    const half8v a = *(const half8v*)&h2[(long)pr.x * 64 + lane * 8];
    const half8v b = *(const half8v*)&h2[(long)pr.y * 64 + lane * 8];
    float s = 0.f;
    #pragma unroll
    for (int j = 0; j < 8; ++j) s += (float)a[j] * (float)b[j];
    s += __shfl_xor(s, 1);
    s += __shfl_xor(s, 2);
    s += __shfl_xor(s, 4);
    if (lane == 0) out[p] = s;
}

// ---------------------------------------------------------------------------
extern "C" void kernel_launch(void* const* d_in, const int* in_sizes, int n_in,
                              void* d_out, int out_size, void* d_ws, size_t ws_size,
                              hipStream_t stream) {
    const float* x     = (const float*)d_in[0];
    const int*   erows = (const int*)d_in[1];
    const int*   ecols = (const int*)d_in[2];
    const float* evals = (const float*)d_in[3];
    const int2*  pairs = (const int2*)d_in[4];
    const float* W1    = (const float*)d_in[5];
    const float* W2    = (const float*)d_in[6];
    float* out = (float*)d_out;

    char* ws = (char*)d_ws;
    _Float16*           g1     = (_Float16*)          (ws);              //  0      .. 25.6M
    _Float16*           g2     = (_Float16*)          (ws + 25600000);   // 25.6M  .. 38.4M
    _Float16*           agg2   = (_Float16*)          (ws + 38400000);   // 38.4M  .. 51.2M
    int*                rowptr = (int*)               (ws + 51200000);   // +400,016
    int*                deg    = (int*)               (ws + 51600016);   // +400,000
    unsigned long long* epack  = (unsigned long long*)(ws + 52000016);   // +6,400,000
    int*                bsum   = (int*)               (ws + 58400016);   // +512
    int*                boff   = (int*)               (ws + 58400528);   // +512
    _Float16*           Wt1    = (_Float16*)          (ws + 58401040);   // +32,768
    _Float16*           Wt2    = (_Float16*)          (ws + 58433808);   // +16,384
    int*                hist   = (int*)               (ws + 58450192);   // +200,704
    int*                off    = (int*)               (ws + 58650896);   // +200,704
    unsigned long long* etmp   = (unsigned long long*)(ws + 58851600);   // +6,400,000 -> 65.3M

    // --- rowptr + bucket/tile histogram (one pass over erows) ---
    hipMemsetAsync(deg, 0, (size_t)N_NODES * 4, stream);
    hist_both<<<N_TILES, 256, 0, stream>>>(erows, deg, hist);
    scan_phase1<<<N_SBLKS, SCAN_BLK, 0, stream>>>(deg, bsum);
    scan_phase2<<<1, 128, 0, stream>>>(bsum, boff, rowptr);
    scan_phase3<<<N_SBLKS, SCAN_BLK, 0, stream>>>(deg, boff, rowptr);

    // --- edge partition into CSR order ---
    bucket_scan<<<N_BKT, 256, 0, stream>>>(hist, rowptr, off);
    partition<<<N_TILES, 256, 0, stream>>>(erows, ecols, evals, off, etmp);
    bucket_reorder<<<N_BKT, 256, 0, stream>>>(rowptr, etmp, epack);

    transpose_w<<<1, 256, 0, stream>>>(W1, W2, Wt1, Wt2);

    // --- Layer 1 GEMM: g1 = x @ W1 (f16) ---
    gemm_mfma<128, true><<<(N_NODES + 63) / 64, 256, 0, stream>>>(x, Wt1, g1, N_NODES);

    // --- FUSED Layer1-aggregate + Layer2 GEMM: g2 = relu(A_sp@g1) @ W2 ---
    spmm_gemm_fused<<<(N_NODES + 63) / 64, 256, 0, stream>>>(
        rowptr, (const long long*)epack, g1, Wt2, g2, N_NODES);

    // --- Layer 2 aggregate: agg2 = A_sp @ g2 ---
    spmm_csr_h<64, false><<<(N_NODES + 31) / 32, 256, 0, stream>>>(
        rowptr, (const long long*)epack, g2, agg2, N_NODES);

    // --- Decode ---
    decode_dot<<<(N_PAIRS * 8 + 255) / 256, 256, 0, stream>>>(agg2, pairs, out, N_PAIRS);
}

// Round 10
// 192.446 us; speedup vs baseline: 1.1732x; 1.1732x over previous
//
#include <hip/hip_runtime.h>

#define N_NODES 100000
#define N_EDGES 800000
#define N_PAIRS 500000
#define SCAN_BLK 1024
#define N_SBLKS ((N_NODES + SCAN_BLK - 1) / SCAN_BLK)   // 98

#define T_TILE  4096
#define N_TILES ((N_EDGES + T_TILE - 1) / T_TILE)       // 196
#define N_BKT   256
#define NPB     391                                     // nodes per bucket
#define BCAP    4096                                    // reorder staging capacity

typedef _Float16 half4v __attribute__((ext_vector_type(4)));
typedef _Float16 half8v __attribute__((ext_vector_type(8)));
typedef float    f32x4  __attribute__((ext_vector_type(4)));

// ---------------------------------------------------------------------------
// Pre-transpose + fp16-convert weights: Wt[m][k] = (half)W[k][m].  Tiny.
// ---------------------------------------------------------------------------
__global__ __launch_bounds__(256) void transpose_w(const float* __restrict__ W1,
                                                   const float* __restrict__ W2,
                                                   _Float16* __restrict__ Wt1,
                                                   _Float16* __restrict__ Wt2) {
    for (int i = threadIdx.x; i < 128 * 128; i += 256) {
        const int k = i >> 7, m = i & 127;
        Wt1[m * 128 + k] = (_Float16)W1[i];
    }
    for (int i = threadIdx.x; i < 128 * 64; i += 256) {
        const int k = i >> 6, m = i & 63;
        Wt2[m * 128 + k] = (_Float16)W2[i];
    }
}

// ---------------------------------------------------------------------------
// XOR-16B LDS swizzle: byte ^= (row&7)<<4 -> fragment reads <=2-way (free).
// v_mfma_f32_16x16x16_f16: A: lane l holds A[l%16][4*(l/16)+i];
//   B: B[4*(l/16)+i][l%16]; D: D[4*(l/16)+i][l%16].
// ---------------------------------------------------------------------------
__device__ __forceinline__ int swz(int byte_off, int row) {
    return byte_off ^ ((row & 7) << 4);
}

template<int M, bool A_IS_F32>
__global__ __launch_bounds__(256) void gemm_mfma(const void* __restrict__ Ap,
                                                 const _Float16* __restrict__ Wt,
                                                 _Float16* __restrict__ C, int nRows) {
    constexpr int K  = 128;
    constexpr int CT = M / 16;
    __shared__ _Float16 Alds[64 * K];
    __shared__ _Float16 Wlds[M * K];

    const int rb = blockIdx.x * 64;

    if (A_IS_F32) {
        const float* A = (const float*)Ap;
        for (int idx = threadIdx.x; idx < 64 * (K / 4); idx += 256) {
            const int row = idx >> 5, c4 = idx & 31;
            const int rg = (rb + row < nRows) ? rb + row : nRows - 1;
            const float4 a = *(const float4*)&A[(long)rg * K + c4 * 4];
            half4v h = { (_Float16)a.x, (_Float16)a.y, (_Float16)a.z, (_Float16)a.w };
            *(half4v*)((char*)Alds + swz(row * 256 + c4 * 8, row)) = h;
        }
    } else {
        const _Float16* A = (const _Float16*)Ap;
        for (int idx = threadIdx.x; idx < 64 * (K / 8); idx += 256) {
            const int row = idx >> 4, seg = idx & 15;
            const int rg = (rb + row < nRows) ? rb + row : nRows - 1;
            const half8v h = *(const half8v*)&A[(long)rg * K + seg * 8];
            *(half8v*)((char*)Alds + swz(row * 256 + seg * 16, row)) = h;
        }
    }
    for (int idx = threadIdx.x; idx < M * (K / 8); idx += 256) {
        const int col = idx >> 4, seg = idx & 15;
        const half8v h = *(const half8v*)&Wt[col * K + seg * 8];
        *(half8v*)((char*)Wlds + swz(col * 256 + seg * 16, col)) = h;
    }
    __syncthreads();

    const int l  = threadIdx.x & 63;
    const int w  = threadIdx.x >> 6;
    const int lr = l & 15;
    const int lg = l >> 4;

    f32x4 acc[CT];
    #pragma unroll
    for (int ct = 0; ct < CT; ++ct) acc[ct] = (f32x4){0.f, 0.f, 0.f, 0.f};

    #pragma unroll
    for (int ks = 0; ks < K / 16; ++ks) {
        const int kb   = ks * 32 + lg * 8;
        const int arow = w * 16 + lr;
        const half4v af = *(const half4v*)((const char*)Alds + swz(arow * 256 + kb, arow));
        #pragma unroll
        for (int ct = 0; ct < CT; ++ct) {
            const int col = ct * 16 + lr;
            const half4v bf = *(const half4v*)((const char*)Wlds + swz(col * 256 + kb, col));
            acc[ct] = __builtin_amdgcn_mfma_f32_16x16x16f16(af, bf, acc[ct], 0, 0, 0);
        }
    }

    #pragma unroll
    for (int ct = 0; ct < CT; ++ct) {
        const int col = ct * 16 + lr;
        #pragma unroll
        for (int j = 0; j < 4; ++j) {
            const int row = rb + w * 16 + lg * 4 + j;
            if (row < nRows) C[(long)row * M + col] = (_Float16)acc[ct][j];
        }
    }
}

// ---------------------------------------------------------------------------
// FUSED: g2[64 rows, 64] = relu(A_sp @ g1)[tile] @ Wt2^T.
// 512 threads (8 waves): gather phase has 32 rows in flight (2 passes) with
// unroll-2 edge chains; 4 blocks/CU co-resident (32 KB LDS, VGPR<=64) for
// ~100% occupancy — R8's 73 us at 30% occupancy was latency-bound, not BW.
// MFMA phase: wave w owns rows (w>>1)*16..+15, cols (w&1)*32..+31.
// ---------------------------------------------------------------------------
__global__ __launch_bounds__(512) void spmm_gemm_fused(const int* __restrict__ rowptr,
                                                       const long long* __restrict__ epack,
                                                       const _Float16* __restrict__ g,
                                                       const _Float16* __restrict__ Wt2,
                                                       _Float16* __restrict__ g2, int nRows) {
    constexpr int K = 128, M = 64;
    __shared__ _Float16 Alds[64 * K];
    __shared__ _Float16 Wlds[M * K];

    const int rb = blockIdx.x * 64;

    // stage Wt2
    for (int idx = threadIdx.x; idx < M * (K / 8); idx += 512) {
        const int col = idx >> 4, seg = idx & 15;
        const half8v h = *(const half8v*)&Wt2[col * K + seg * 8];
        *(half8v*)((char*)Wlds + swz(col * 256 + seg * 16, col)) = h;
    }

    // phase 1: spmm into Alds — 16 lanes x 8 dims per row, 32 rows per pass
    const int li = threadIdx.x & 15;
    const int rs = threadIdx.x >> 4;        // 0..31
    #pragma unroll
    for (int s = 0; s < 2; ++s) {
        const int lrow = s * 32 + rs;
        const int r  = rb + lrow;
        const int rc = (r < nRows) ? r : nRows - 1;
        const int lo = rowptr[rc], hi = rowptr[rc + 1];
        float acc[8] = {0.f, 0.f, 0.f, 0.f, 0.f, 0.f, 0.f, 0.f};
        #pragma unroll 2
        for (int e = lo; e < hi; ++e) {
            const long long pk = epack[e];
            const int   c = (int)pk;
            const float v = __int_as_float((int)(pk >> 32));
            const half8v m = *(const half8v*)&g[(long)c * K + li * 8];
            #pragma unroll
            for (int j = 0; j < 8; ++j) acc[j] += v * (float)m[j];
        }
        half8v h;
        #pragma unroll
        for (int j = 0; j < 8; ++j) h[j] = (_Float16)fmaxf(acc[j], 0.f);
        *(half8v*)((char*)Alds + swz(lrow * 256 + li * 16, lrow)) = h;
    }
    __syncthreads();

    // phase 2: MFMA — 8 waves cover 4 row-groups x 4 col-tiles
    const int l    = threadIdx.x & 63;
    const int w    = threadIdx.x >> 6;      // 0..7
    const int lr   = l & 15;
    const int lg   = l >> 4;
    const int rowg = w >> 1;                // 0..3
    const int colb = (w & 1) * 32;          // 0 or 32

    f32x4 acc[2];
    acc[0] = (f32x4){0.f, 0.f, 0.f, 0.f};
    acc[1] = (f32x4){0.f, 0.f, 0.f, 0.f};

    #pragma unroll
    for (int ks = 0; ks < K / 16; ++ks) {
        const int kb   = ks * 32 + lg * 8;
        const int arow = rowg * 16 + lr;
        const half4v af = *(const half4v*)((const char*)Alds + swz(arow * 256 + kb, arow));
        #pragma unroll
        for (int ct = 0; ct < 2; ++ct) {
            const int col = colb + ct * 16 + lr;
            const half4v bf = *(const half4v*)((const char*)Wlds + swz(col * 256 + kb, col));
            acc[ct] = __builtin_amdgcn_mfma_f32_16x16x16f16(af, bf, acc[ct], 0, 0, 0);
        }
    }

    #pragma unroll
    for (int ct = 0; ct < 2; ++ct) {
        const int col = colb + ct * 16 + lr;
        #pragma unroll
        for (int j = 0; j < 4; ++j) {
            const int row = rb + rowg * 16 + lg * 4 + j;
            if (row < nRows) g2[(long)row * M + col] = (_Float16)acc[ct][j];
        }
    }
}

// ---------------------------------------------------------------------------
// rowptr build: fused per-node + per-(bucket,tile) histogram -> 3-phase scan
// ---------------------------------------------------------------------------
__global__ __launch_bounds__(256) void hist_both(const int* __restrict__ erows,
                                                 int* __restrict__ deg,
                                                 int* __restrict__ hist) {
    __shared__ int cnt[N_BKT];
    cnt[threadIdx.x] = 0;
    __syncthreads();
    const int e0 = blockIdx.x * T_TILE;
    const int e1 = min(e0 + T_TILE, N_EDGES);
    for (int e = e0 + threadIdx.x; e < e1; e += 256) {
        const int r = erows[e];
        atomicAdd(&deg[r], 1);
        atomicAdd(&cnt[r / NPB], 1);
    }
    __syncthreads();
    hist[threadIdx.x * N_TILES + blockIdx.x] = cnt[threadIdx.x];
}

__global__ __launch_bounds__(SCAN_BLK) void scan_phase1(const int* __restrict__ deg,
                                                        int* __restrict__ bsum) {
    const int i = blockIdx.x * SCAN_BLK + threadIdx.x;
    int v = (i < N_NODES) ? deg[i] : 0;
    #pragma unroll
    for (int off = 1; off < 64; off <<= 1) v += __shfl_xor(v, off);
    __shared__ int ws[SCAN_BLK / 64];
    if ((threadIdx.x & 63) == 0) ws[threadIdx.x >> 6] = v;
    __syncthreads();
    if (threadIdx.x < SCAN_BLK / 64) {
        int s = ws[threadIdx.x];
        #pragma unroll
        for (int off = 1; off < SCAN_BLK / 64; off <<= 1) s += __shfl_xor(s, off);
        if (threadIdx.x == 0) bsum[blockIdx.x] = s;
    }
}

__global__ __launch_bounds__(128) void scan_phase2(const int* __restrict__ bsum,
                                                   int* __restrict__ boff,
                                                   int* __restrict__ rowptr) {
    __shared__ int lds[128];
    const int t = threadIdx.x;
    const int v = (t < N_SBLKS) ? bsum[t] : 0;
    lds[t] = v;
    __syncthreads();
    for (int off = 1; off < 128; off <<= 1) {
        int u = (t >= off) ? lds[t - off] : 0;
        __syncthreads();
        lds[t] += u;
        __syncthreads();
    }
    if (t < N_SBLKS) boff[t] = lds[t] - v;
    if (t == N_SBLKS - 1) rowptr[N_NODES] = lds[t];
}

__global__ __launch_bounds__(SCAN_BLK) void scan_phase3(const int* __restrict__ deg,
                                                        const int* __restrict__ boff,
                                                        int* __restrict__ rowptr) {
    const int i    = blockIdx.x * SCAN_BLK + threadIdx.x;
    const int lane = threadIdx.x & 63;
    const int wid  = threadIdx.x >> 6;
    const int v = (i < N_NODES) ? deg[i] : 0;
    int s = v;
    #pragma unroll
    for (int off = 1; off < 64; off <<= 1) {
        int u = __shfl_up(s, off);
        if (lane >= off) s += u;
    }
    __shared__ int wsum[SCAN_BLK / 64];
    __shared__ int woff[SCAN_BLK / 64];
    if (lane == 63) wsum[wid] = s;
    __syncthreads();
    if (threadIdx.x < SCAN_BLK / 64) {
        const int t0 = wsum[threadIdx.x];
        int q = t0;
        #pragma unroll
        for (int off = 1; off < SCAN_BLK / 64; off <<= 1) {
            int u = __shfl_up(q, off);
            if ((int)threadIdx.x >= off) q += u;
        }
        woff[threadIdx.x] = q - t0;
    }
    __syncthreads();
    const int ex = (s - v) + woff[wid] + boff[blockIdx.x];
    if (i < N_NODES) rowptr[i] = ex;
}

// ---------------------------------------------------------------------------
// Edge partition into CSR order (2-level; see R7 notes).
// tmp record: [val:32][lrow:9][col:17].  Final: [val:32][col:32].
// ---------------------------------------------------------------------------
__global__ __launch_bounds__(256) void bucket_scan(const int* __restrict__ hist,
                                                   const int* __restrict__ rowptr,
                                                   int* __restrict__ off) {
    __shared__ int lds[256];
    const int b = blockIdx.x;
    const int t = threadIdx.x;
    const int v = (t < N_TILES) ? hist[b * N_TILES + t] : 0;
    lds[t] = v;
    __syncthreads();
    for (int o = 1; o < 256; o <<= 1) {
        int u = (t >= o) ? lds[t - o] : 0;
        __syncthreads();
        lds[t] += u;
        __syncthreads();
    }
    if (t < N_TILES) off[b * N_TILES + t] = rowptr[b * NPB] + lds[t] - v;
}

__global__ __launch_bounds__(256) void partition(const int* __restrict__ erows,
                                                 const int* __restrict__ ecols,
                                                 const float* __restrict__ evals,
                                                 const int* __restrict__ off,
                                                 unsigned long long* __restrict__ etmp) {
    __shared__ int cur[N_BKT];
    cur[threadIdx.x] = off[threadIdx.x * N_TILES + blockIdx.x];
    __syncthreads();
    const int e0 = blockIdx.x * T_TILE;
    const int e1 = min(e0 + T_TILE, N_EDGES);
    for (int e = e0 + threadIdx.x; e < e1; e += 256) {
        const int r = erows[e];
        const int b = r / NPB;
        const int lrow = r - b * NPB;
        const int p = atomicAdd(&cur[b], 1);
        etmp[p] = ((unsigned long long)(unsigned)__float_as_int(evals[e]) << 32)
                | ((unsigned)lrow << 17) | (unsigned)ecols[e];
    }
}

__global__ __launch_bounds__(256) void bucket_reorder(const int* __restrict__ rowptr,
                                                      const unsigned long long* __restrict__ etmp,
                                                      unsigned long long* __restrict__ epack) {
    __shared__ int lcur[NPB];
    __shared__ unsigned long long stg[BCAP];
    const int b    = blockIdx.x;
    const int lo   = b * NPB;
    const int hiN  = min(lo + NPB, N_NODES);
    const int base = rowptr[lo];
    const int cnt  = rowptr[hiN] - base;
    for (int j = threadIdx.x; j < hiN - lo; j += 256)
        lcur[j] = rowptr[lo + j] - base;
    __syncthreads();
    for (int i = threadIdx.x; i < cnt; i += 256) {
        const unsigned long long p = etmp[base + i];
        const int lrow = (int)((p >> 17) & 0x1FF);
        const int pos  = atomicAdd(&lcur[lrow], 1);
        const unsigned long long rec = (p & 0xFFFFFFFF00000000ULL) | (p & 0x1FFFFULL);
        if (pos < BCAP) stg[pos] = rec;
        else epack[base + pos] = rec;   // safety fallback (statistically never)
    }
    __syncthreads();
    const int n = min(cnt, BCAP);
    for (int i = threadIdx.x; i < n; i += 256)
        epack[base + i] = stg[i];
}

// ---------------------------------------------------------------------------
// CSR SpMM (gather, fp16 data, f32 accumulate): agg[r] = sum vals*g[cols]
// ---------------------------------------------------------------------------
template<int D, bool RELU>
__global__ __launch_bounds__(256) void spmm_csr_h(const int* __restrict__ rowptr,
                                                  const long long* __restrict__ epack,
                                                  const _Float16* __restrict__ g,
                                                  _Float16* __restrict__ agg, int nRows) {
    constexpr int LPR = D / 8;
    constexpr int RPB = 256 / LPR;
    const int r  = blockIdx.x * RPB + threadIdx.x / LPR;
    const int li = threadIdx.x % LPR;
    if (r >= nRows) return;
    const int lo = rowptr[r], hi = rowptr[r + 1];
    float acc[8] = {0.f, 0.f, 0.f, 0.f, 0.f, 0.f, 0.f, 0.f};
    #pragma unroll 2
    for (int e = lo; e < hi; ++e) {
        const long long pk = epack[e];
        const int   c = (int)pk;
        const float v = __int_as_float((int)(pk >> 32));
        const half8v m = *(const half8v*)&g[(long)c * D + li * 8];
        #pragma unroll
        for (int j = 0; j < 8; ++j) acc[j] += v * (float)m[j];
    }
    half8v o;
    #pragma unroll
    for (int j = 0; j < 8; ++j) {
        float a = RELU ? fmaxf(acc[j], 0.f) : acc[j];
        o[j] = (_Float16)a;
    }
    *(half8v*)&agg[(long)r * D + li * 8] = o;
}

// ---------------------------------------------------------------------------
// Decode: out[p] = dot(h2[pairs.x], h2[pairs.y]) over 64 f16 dims, f32 acc.
// ---------------------------------------------------------------------------
__global__ __launch_bounds__(256) void decode_dot(const _Float16* __restrict__ h2,
                                                  const int2* __restrict__ pairs,
                                                  float* __restrict__ out, int nPairs) {
    const int tid  = blockIdx.x * 256 + threadIdx.x;
    const int p    = tid >> 3;
    const int lane = tid & 7;
    if (p >= nPairs) return;
    const int2 pr = pairs[p];
    const half8v a = *(const half8v*)&h2[(long)pr.x * 64 + lane * 8];
    const half8v b = *(const half8v*)&h2[(long)pr.y * 64 + lane * 8];
    float s = 0.f;
    #pragma unroll
    for (int j = 0; j < 8; ++j) s += (float)a[j] * (float)b[j];
    s += __shfl_xor(s, 1);
    s += __shfl_xor(s, 2);
    s += __shfl_xor(s, 4);
    if (lane == 0) out[p] = s;
}

// ---------------------------------------------------------------------------
extern "C" void kernel_launch(void* const* d_in, const int* in_sizes, int n_in,
                              void* d_out, int out_size, void* d_ws, size_t ws_size,
                              hipStream_t stream) {
    const float* x     = (const float*)d_in[0];
    const int*   erows = (const int*)d_in[1];
    const int*   ecols = (const int*)d_in[2];
    const float* evals = (const float*)d_in[3];
    const int2*  pairs = (const int2*)d_in[4];
    const float* W1    = (const float*)d_in[5];
    const float* W2    = (const float*)d_in[6];
    float* out = (float*)d_out;

    char* ws = (char*)d_ws;
    _Float16*           g1     = (_Float16*)          (ws);              //  0      .. 25.6M
    _Float16*           g2     = (_Float16*)          (ws + 25600000);   // 25.6M  .. 38.4M
    _Float16*           agg2   = (_Float16*)          (ws + 38400000);   // 38.4M  .. 51.2M
    int*                rowptr = (int*)               (ws + 51200000);   // +400,016
    int*                deg    = (int*)               (ws + 51600016);   // +400,000
    unsigned long long* epack  = (unsigned long long*)(ws + 52000016);   // +6,400,000
    int*                bsum   = (int*)               (ws + 58400016);   // +512
    int*                boff   = (int*)               (ws + 58400528);   // +512
    _Float16*           Wt1    = (_Float16*)          (ws + 58401040);   // +32,768
    _Float16*           Wt2    = (_Float16*)          (ws + 58433808);   // +16,384
    int*                hist   = (int*)               (ws + 58450192);   // +200,704
    int*                off    = (int*)               (ws + 58650896);   // +200,704
    unsigned long long* etmp   = (unsigned long long*)(ws + 58851600);   // +6,400,000 -> 65.3M

    // --- rowptr + bucket/tile histogram (one pass over erows) ---
    hipMemsetAsync(deg, 0, (size_t)N_NODES * 4, stream);
    hist_both<<<N_TILES, 256, 0, stream>>>(erows, deg, hist);
    scan_phase1<<<N_SBLKS, SCAN_BLK, 0, stream>>>(deg, bsum);
    scan_phase2<<<1, 128, 0, stream>>>(bsum, boff, rowptr);
    scan_phase3<<<N_SBLKS, SCAN_BLK, 0, stream>>>(deg, boff, rowptr);

    // --- edge partition into CSR order ---
    bucket_scan<<<N_BKT, 256, 0, stream>>>(hist, rowptr, off);
    partition<<<N_TILES, 256, 0, stream>>>(erows, ecols, evals, off, etmp);
    bucket_reorder<<<N_BKT, 256, 0, stream>>>(rowptr, etmp, epack);

    transpose_w<<<1, 256, 0, stream>>>(W1, W2, Wt1, Wt2);

    // --- Layer 1 GEMM: g1 = x @ W1 (f16) ---
    gemm_mfma<128, true><<<(N_NODES + 63) / 64, 256, 0, stream>>>(x, Wt1, g1, N_NODES);

    // --- FUSED Layer1-aggregate + Layer2 GEMM: g2 = relu(A_sp@g1) @ W2 ---
    spmm_gemm_fused<<<(N_NODES + 63) / 64, 512, 0, stream>>>(
        rowptr, (const long long*)epack, g1, Wt2, g2, N_NODES);

    // --- Layer 2 aggregate: agg2 = A_sp @ g2 ---
    spmm_csr_h<64, false><<<(N_NODES + 31) / 32, 256, 0, stream>>>(
        rowptr, (const long long*)epack, g2, agg2, N_NODES);

    // --- Decode ---
    decode_dot<<<(N_PAIRS * 8 + 255) / 256, 256, 0, stream>>>(agg2, pairs, out, N_PAIRS);
}

// Round 11
// 167.910 us; speedup vs baseline: 1.3446x; 1.1461x over previous
//
#include <hip/hip_runtime.h>

#define N_NODES 100000
#define N_EDGES 800000
#define N_PAIRS 500000
#define SCAN_BLK 1024
#define N_SBLKS ((N_NODES + SCAN_BLK - 1) / SCAN_BLK)   // 98

#define T_TILE  4096
#define N_TILES ((N_EDGES + T_TILE - 1) / T_TILE)       // 196
#define N_BKT   256
#define NPB     391                                     // nodes per bucket
#define BCAP    4096                                    // reorder staging capacity

typedef _Float16 half4v __attribute__((ext_vector_type(4)));
typedef _Float16 half8v __attribute__((ext_vector_type(8)));
typedef float    f32x4  __attribute__((ext_vector_type(4)));

// ---------------------------------------------------------------------------
// XOR-16B LDS swizzle: byte ^= (row&7)<<4 -> fragment reads <=2-way (free).
// v_mfma_f32_16x16x16_f16: A: lane l holds A[l%16][4*(l/16)+i];
//   B: B[4*(l/16)+i][l%16]; D: D[4*(l/16)+i][l%16].
// ---------------------------------------------------------------------------
__device__ __forceinline__ int swz(int byte_off, int row) {
    return byte_off ^ ((row & 7) << 4);
}

template<int M, bool A_IS_F32>
__global__ __launch_bounds__(256) void gemm_mfma(const void* __restrict__ Ap,
                                                 const _Float16* __restrict__ Wt,
                                                 _Float16* __restrict__ C, int nRows) {
    constexpr int K  = 128;
    constexpr int CT = M / 16;
    __shared__ _Float16 Alds[64 * K];
    __shared__ _Float16 Wlds[M * K];

    const int rb = blockIdx.x * 64;

    if (A_IS_F32) {
        const float* A = (const float*)Ap;
        for (int idx = threadIdx.x; idx < 64 * (K / 4); idx += 256) {
            const int row = idx >> 5, c4 = idx & 31;
            const int rg = (rb + row < nRows) ? rb + row : nRows - 1;
            const float4 a = *(const float4*)&A[(long)rg * K + c4 * 4];
            half4v h = { (_Float16)a.x, (_Float16)a.y, (_Float16)a.z, (_Float16)a.w };
            *(half4v*)((char*)Alds + swz(row * 256 + c4 * 8, row)) = h;
        }
    } else {
        const _Float16* A = (const _Float16*)Ap;
        for (int idx = threadIdx.x; idx < 64 * (K / 8); idx += 256) {
            const int row = idx >> 4, seg = idx & 15;
            const int rg = (rb + row < nRows) ? rb + row : nRows - 1;
            const half8v h = *(const half8v*)&A[(long)rg * K + seg * 8];
            *(half8v*)((char*)Alds + swz(row * 256 + seg * 16, row)) = h;
        }
    }
    for (int idx = threadIdx.x; idx < M * (K / 8); idx += 256) {
        const int col = idx >> 4, seg = idx & 15;
        const half8v h = *(const half8v*)&Wt[col * K + seg * 8];
        *(half8v*)((char*)Wlds + swz(col * 256 + seg * 16, col)) = h;
    }
    __syncthreads();

    const int l  = threadIdx.x & 63;
    const int w  = threadIdx.x >> 6;
    const int lr = l & 15;
    const int lg = l >> 4;

    f32x4 acc[CT];
    #pragma unroll
    for (int ct = 0; ct < CT; ++ct) acc[ct] = (f32x4){0.f, 0.f, 0.f, 0.f};

    #pragma unroll
    for (int ks = 0; ks < K / 16; ++ks) {
        const int kb   = ks * 32 + lg * 8;
        const int arow = w * 16 + lr;
        const half4v af = *(const half4v*)((const char*)Alds + swz(arow * 256 + kb, arow));
        #pragma unroll
        for (int ct = 0; ct < CT; ++ct) {
            const int col = ct * 16 + lr;
            const half4v bf = *(const half4v*)((const char*)Wlds + swz(col * 256 + kb, col));
            acc[ct] = __builtin_amdgcn_mfma_f32_16x16x16f16(af, bf, acc[ct], 0, 0, 0);
        }
    }

    #pragma unroll
    for (int ct = 0; ct < CT; ++ct) {
        const int col = ct * 16 + lr;
        #pragma unroll
        for (int j = 0; j < 4; ++j) {
            const int row = rb + w * 16 + lg * 4 + j;
            if (row < nRows) C[(long)row * M + col] = (_Float16)acc[ct][j];
        }
    }
}

// ---------------------------------------------------------------------------
// FUSED: g2[64 rows, 64] = relu(A_sp @ g1)[tile] @ Wt2^T.  512 thr / 8 waves.
// ---------------------------------------------------------------------------
__global__ __launch_bounds__(512) void spmm_gemm_fused(const int* __restrict__ rowptr,
                                                       const long long* __restrict__ epack,
                                                       const _Float16* __restrict__ g,
                                                       const _Float16* __restrict__ Wt2,
                                                       _Float16* __restrict__ g2, int nRows) {
    constexpr int K = 128, M = 64;
    __shared__ _Float16 Alds[64 * K];
    __shared__ _Float16 Wlds[M * K];

    const int rb = blockIdx.x * 64;

    for (int idx = threadIdx.x; idx < M * (K / 8); idx += 512) {
        const int col = idx >> 4, seg = idx & 15;
        const half8v h = *(const half8v*)&Wt2[col * K + seg * 8];
        *(half8v*)((char*)Wlds + swz(col * 256 + seg * 16, col)) = h;
    }

    const int li = threadIdx.x & 15;
    const int rs = threadIdx.x >> 4;        // 0..31
    #pragma unroll
    for (int s = 0; s < 2; ++s) {
        const int lrow = s * 32 + rs;
        const int r  = rb + lrow;
        const int rc = (r < nRows) ? r : nRows - 1;
        const int lo = rowptr[rc], hi = rowptr[rc + 1];
        float acc[8] = {0.f, 0.f, 0.f, 0.f, 0.f, 0.f, 0.f, 0.f};
        #pragma unroll 4
        for (int e = lo; e < hi; ++e) {
            const long long pk = epack[e];
            const int   c = (int)pk;
            const float v = __int_as_float((int)(pk >> 32));
            const half8v m = *(const half8v*)&g[(long)c * K + li * 8];
            #pragma unroll
            for (int j = 0; j < 8; ++j) acc[j] += v * (float)m[j];
        }
        half8v h;
        #pragma unroll
        for (int j = 0; j < 8; ++j) h[j] = (_Float16)fmaxf(acc[j], 0.f);
        *(half8v*)((char*)Alds + swz(lrow * 256 + li * 16, lrow)) = h;
    }
    __syncthreads();

    const int l    = threadIdx.x & 63;
    const int w    = threadIdx.x >> 6;      // 0..7
    const int lr   = l & 15;
    const int lg   = l >> 4;
    const int rowg = w >> 1;                // 0..3
    const int colb = (w & 1) * 32;          // 0 or 32

    f32x4 acc[2];
    acc[0] = (f32x4){0.f, 0.f, 0.f, 0.f};
    acc[1] = (f32x4){0.f, 0.f, 0.f, 0.f};

    #pragma unroll
    for (int ks = 0; ks < K / 16; ++ks) {
        const int kb   = ks * 32 + lg * 8;
        const int arow = rowg * 16 + lr;
        const half4v af = *(const half4v*)((const char*)Alds + swz(arow * 256 + kb, arow));
        #pragma unroll
        for (int ct = 0; ct < 2; ++ct) {
            const int col = colb + ct * 16 + lr;
            const half4v bf = *(const half4v*)((const char*)Wlds + swz(col * 256 + kb, col));
            acc[ct] = __builtin_amdgcn_mfma_f32_16x16x16f16(af, bf, acc[ct], 0, 0, 0);
        }
    }

    #pragma unroll
    for (int ct = 0; ct < 2; ++ct) {
        const int col = colb + ct * 16 + lr;
        #pragma unroll
        for (int j = 0; j < 4; ++j) {
            const int row = rb + rowg * 16 + lg * 4 + j;
            if (row < nRows) g2[(long)row * M + col] = (_Float16)acc[ct][j];
        }
    }
}

// ---------------------------------------------------------------------------
// hist_both (+ fused weight transpose in the extra block):
// blocks 0..N_TILES-1: per-node deg atomics + per-(bucket,tile) histogram.
// block N_TILES: Wt[m][k] = (half)W[k][m].
// ---------------------------------------------------------------------------
__global__ __launch_bounds__(256) void hist_both(const int* __restrict__ erows,
                                                 int* __restrict__ deg,
                                                 int* __restrict__ hist,
                                                 const float* __restrict__ W1,
                                                 const float* __restrict__ W2,
                                                 _Float16* __restrict__ Wt1,
                                                 _Float16* __restrict__ Wt2) {
    if (blockIdx.x == N_TILES) {
        for (int i = threadIdx.x; i < 128 * 128; i += 256) {
            const int k = i >> 7, m = i & 127;
            Wt1[m * 128 + k] = (_Float16)W1[i];
        }
        for (int i = threadIdx.x; i < 128 * 64; i += 256) {
            const int k = i >> 6, m = i & 63;
            Wt2[m * 128 + k] = (_Float16)W2[i];
        }
        return;
    }
    __shared__ int cnt[N_BKT];
    cnt[threadIdx.x] = 0;
    __syncthreads();
    const int e0 = blockIdx.x * T_TILE;
    const int e1 = min(e0 + T_TILE, N_EDGES);
    for (int e = e0 + threadIdx.x; e < e1; e += 256) {
        const int r = erows[e];
        atomicAdd(&deg[r], 1);
        atomicAdd(&cnt[r / NPB], 1);
    }
    __syncthreads();
    hist[threadIdx.x * N_TILES + blockIdx.x] = cnt[threadIdx.x];
}

// ---------------------------------------------------------------------------
// scan_phase12: per-block reduce of deg -> bsum; LAST block also scans the
// 98 block sums (inline phase2) -> boff + rowptr[N].  done zeroed by memset.
// ---------------------------------------------------------------------------
__global__ __launch_bounds__(SCAN_BLK) void scan_phase12(const int* __restrict__ deg,
                                                         int* __restrict__ bsum,
                                                         int* __restrict__ boff,
                                                         int* __restrict__ rowptr,
                                                         int* __restrict__ done) {
    const int i = blockIdx.x * SCAN_BLK + threadIdx.x;
    int v = (i < N_NODES) ? deg[i] : 0;
    #pragma unroll
    for (int off = 1; off < 64; off <<= 1) v += __shfl_xor(v, off);
    __shared__ int ws[SCAN_BLK / 64];
    if ((threadIdx.x & 63) == 0) ws[threadIdx.x >> 6] = v;
    __syncthreads();
    if (threadIdx.x < SCAN_BLK / 64) {
        int s = ws[threadIdx.x];
        #pragma unroll
        for (int off = 1; off < SCAN_BLK / 64; off <<= 1) s += __shfl_xor(s, off);
        if (threadIdx.x == 0) bsum[blockIdx.x] = s;
    }
    // last-block-done: inline phase 2
    __shared__ int lastf;
    if (threadIdx.x == 0) {
        __threadfence();
        lastf = (atomicAdd(done, 1) == gridDim.x - 1) ? 1 : 0;
    }
    __syncthreads();
    if (lastf) {
        __threadfence();
        __shared__ int lds2[128];
        const int t = threadIdx.x;
        int val = 0;
        if (t < 128) {
            val = (t < N_SBLKS) ? bsum[t] : 0;
            lds2[t] = val;
        }
        __syncthreads();
        for (int off = 1; off < 128; off <<= 1) {
            int u = (t < 128 && t >= off) ? lds2[t - off] : 0;
            __syncthreads();
            if (t < 128) lds2[t] += u;
            __syncthreads();
        }
        if (t < N_SBLKS) boff[t] = lds2[t] - val;
        if (t == N_SBLKS - 1) rowptr[N_NODES] = lds2[t];
    }
}

__global__ __launch_bounds__(SCAN_BLK) void scan_phase3(const int* __restrict__ deg,
                                                        const int* __restrict__ boff,
                                                        int* __restrict__ rowptr) {
    const int i    = blockIdx.x * SCAN_BLK + threadIdx.x;
    const int lane = threadIdx.x & 63;
    const int wid  = threadIdx.x >> 6;
    const int v = (i < N_NODES) ? deg[i] : 0;
    int s = v;
    #pragma unroll
    for (int off = 1; off < 64; off <<= 1) {
        int u = __shfl_up(s, off);
        if (lane >= off) s += u;
    }
    __shared__ int wsum[SCAN_BLK / 64];
    __shared__ int woff[SCAN_BLK / 64];
    if (lane == 63) wsum[wid] = s;
    __syncthreads();
    if (threadIdx.x < SCAN_BLK / 64) {
        const int t0 = wsum[threadIdx.x];
        int q = t0;
        #pragma unroll
        for (int off = 1; off < SCAN_BLK / 64; off <<= 1) {
            int u = __shfl_up(q, off);
            if ((int)threadIdx.x >= off) q += u;
        }
        woff[threadIdx.x] = q - t0;
    }
    __syncthreads();
    const int ex = (s - v) + woff[wid] + boff[blockIdx.x];
    if (i < N_NODES) rowptr[i] = ex;
}

// ---------------------------------------------------------------------------
// Edge partition into CSR order (2-level).
// tmp record: [val:32][lrow:9][col:17].  Final: [val:32][col:32].
// ---------------------------------------------------------------------------
__global__ __launch_bounds__(256) void bucket_scan(const int* __restrict__ hist,
                                                   const int* __restrict__ rowptr,
                                                   int* __restrict__ off) {
    __shared__ int lds[256];
    const int b = blockIdx.x;
    const int t = threadIdx.x;
    const int v = (t < N_TILES) ? hist[b * N_TILES + t] : 0;
    lds[t] = v;
    __syncthreads();
    for (int o = 1; o < 256; o <<= 1) {
        int u = (t >= o) ? lds[t - o] : 0;
        __syncthreads();
        lds[t] += u;
        __syncthreads();
    }
    if (t < N_TILES) off[b * N_TILES + t] = rowptr[b * NPB] + lds[t] - v;
}

__global__ __launch_bounds__(256) void partition(const int* __restrict__ erows,
                                                 const int* __restrict__ ecols,
                                                 const float* __restrict__ evals,
                                                 const int* __restrict__ off,
                                                 unsigned long long* __restrict__ etmp) {
    __shared__ int cur[N_BKT];
    cur[threadIdx.x] = off[threadIdx.x * N_TILES + blockIdx.x];
    __syncthreads();
    const int e0 = blockIdx.x * T_TILE;
    const int e1 = min(e0 + T_TILE, N_EDGES);
    for (int e = e0 + threadIdx.x; e < e1; e += 256) {
        const int r = erows[e];
        const int b = r / NPB;
        const int lrow = r - b * NPB;
        const int p = atomicAdd(&cur[b], 1);
        etmp[p] = ((unsigned long long)(unsigned)__float_as_int(evals[e]) << 32)
                | ((unsigned)lrow << 17) | (unsigned)ecols[e];
    }
}

__global__ __launch_bounds__(256) void bucket_reorder(const int* __restrict__ rowptr,
                                                      const unsigned long long* __restrict__ etmp,
                                                      unsigned long long* __restrict__ epack) {
    __shared__ int lcur[NPB];
    __shared__ unsigned long long stg[BCAP];
    const int b    = blockIdx.x;
    const int lo   = b * NPB;
    const int hiN  = min(lo + NPB, N_NODES);
    const int base = rowptr[lo];
    const int cnt  = rowptr[hiN] - base;
    for (int j = threadIdx.x; j < hiN - lo; j += 256)
        lcur[j] = rowptr[lo + j] - base;
    __syncthreads();
    for (int i = threadIdx.x; i < cnt; i += 256) {
        const unsigned long long p = etmp[base + i];
        const int lrow = (int)((p >> 17) & 0x1FF);
        const int pos  = atomicAdd(&lcur[lrow], 1);
        const unsigned long long rec = (p & 0xFFFFFFFF00000000ULL) | (p & 0x1FFFFULL);
        if (pos < BCAP) stg[pos] = rec;
        else epack[base + pos] = rec;   // safety fallback (statistically never)
    }
    __syncthreads();
    const int n = min(cnt, BCAP);
    for (int i = threadIdx.x; i < n; i += 256)
        epack[base + i] = stg[i];
}

// ---------------------------------------------------------------------------
// CSR SpMM (gather, fp16 data, f32 accumulate): agg[r] = sum vals*g[cols]
// ---------------------------------------------------------------------------
template<int D, bool RELU>
__global__ __launch_bounds__(256) void spmm_csr_h(const int* __restrict__ rowptr,
                                                  const long long* __restrict__ epack,
                                                  const _Float16* __restrict__ g,
                                                  _Float16* __restrict__ agg, int nRows) {
    constexpr int LPR = D / 8;
    constexpr int RPB = 256 / LPR;
    const int r  = blockIdx.x * RPB + threadIdx.x / LPR;
    const int li = threadIdx.x % LPR;
    if (r >= nRows) return;
    const int lo = rowptr[r], hi = rowptr[r + 1];
    float acc[8] = {0.f, 0.f, 0.f, 0.f, 0.f, 0.f, 0.f, 0.f};
    #pragma unroll 4
    for (int e = lo; e < hi; ++e) {
        const long long pk = epack[e];
        const int   c = (int)pk;
        const float v = __int_as_float((int)(pk >> 32));
        const half8v m = *(const half8v*)&g[(long)c * D + li * 8];
        #pragma unroll
        for (int j = 0; j < 8; ++j) acc[j] += v * (float)m[j];
    }
    half8v o;
    #pragma unroll
    for (int j = 0; j < 8; ++j) {
        float a = RELU ? fmaxf(acc[j], 0.f) : acc[j];
        o[j] = (_Float16)a;
    }
    *(half8v*)&agg[(long)r * D + li * 8] = o;
}

// ---------------------------------------------------------------------------
// Decode: 2 pairs per thread (independent gather chains), 8 lanes per pair.
// ---------------------------------------------------------------------------
__global__ __launch_bounds__(256) void decode_dot(const _Float16* __restrict__ h2,
                                                  const int2* __restrict__ pairs,
                                                  float* __restrict__ out, int nPairs) {
    const int tid  = blockIdx.x * 256 + threadIdx.x;
    const int half = (nPairs + 1) / 2;
    const int p0   = tid >> 3;
    const int lane = tid & 7;
    if (p0 >= half) return;
    const int p1 = p0 + half;
    const bool has1 = p1 < nPairs;
    const int2 pr0 = pairs[p0];
    const int2 pr1 = has1 ? pairs[p1] : pr0;
    const half8v a0 = *(const half8v*)&h2[(long)pr0.x * 64 + lane * 8];
    const half8v b0 = *(const half8v*)&h2[(long)pr0.y * 64 + lane * 8];
    const half8v a1 = *(const half8v*)&h2[(long)pr1.x * 64 + lane * 8];
    const half8v b1 = *(const half8v*)&h2[(long)pr1.y * 64 + lane * 8];
    float s0 = 0.f, s1 = 0.f;
    #pragma unroll
    for (int j = 0; j < 8; ++j) {
        s0 += (float)a0[j] * (float)b0[j];
        s1 += (float)a1[j] * (float)b1[j];
    }
    s0 += __shfl_xor(s0, 1); s1 += __shfl_xor(s1, 1);
    s0 += __shfl_xor(s0, 2); s1 += __shfl_xor(s1, 2);
    s0 += __shfl_xor(s0, 4); s1 += __shfl_xor(s1, 4);
    if (lane == 0) {
        out[p0] = s0;
        if (has1) out[p1] = s1;
    }
}

// ---------------------------------------------------------------------------
extern "C" void kernel_launch(void* const* d_in, const int* in_sizes, int n_in,
                              void* d_out, int out_size, void* d_ws, size_t ws_size,
                              hipStream_t stream) {
    const float* x     = (const float*)d_in[0];
    const int*   erows = (const int*)d_in[1];
    const int*   ecols = (const int*)d_in[2];
    const float* evals = (const float*)d_in[3];
    const int2*  pairs = (const int2*)d_in[4];
    const float* W1    = (const float*)d_in[5];
    const float* W2    = (const float*)d_in[6];
    float* out = (float*)d_out;

    char* ws = (char*)d_ws;
    _Float16*           g1     = (_Float16*)          (ws);              //  0      .. 25.6M
    _Float16*           g2     = (_Float16*)          (ws + 25600000);   // 25.6M  .. 38.4M
    _Float16*           agg2   = (_Float16*)          (ws + 38400000);   // 38.4M  .. 51.2M
    int*                rowptr = (int*)               (ws + 51200000);   // +400,016
    int*                deg    = (int*)               (ws + 51600016);   // +400,000
    int*                done   = (int*)               (ws + 52000016);   // +16
    unsigned long long* epack  = (unsigned long long*)(ws + 52000032);   // +6,400,000
    int*                bsum   = (int*)               (ws + 58400032);   // +512
    int*                boff   = (int*)               (ws + 58400544);   // +512
    _Float16*           Wt1    = (_Float16*)          (ws + 58401056);   // +32,768
    _Float16*           Wt2    = (_Float16*)          (ws + 58433824);   // +16,384
    int*                hist   = (int*)               (ws + 58450208);   // +200,704
    int*                off    = (int*)               (ws + 58650912);   // +200,704
    unsigned long long* etmp   = (unsigned long long*)(ws + 58851616);   // +6,400,000 -> 65.3M

    // --- deg + done zero; fused hist + weight transpose ---
    hipMemsetAsync(deg, 0, (size_t)N_NODES * 4 + 16, stream);
    hist_both<<<N_TILES + 1, 256, 0, stream>>>(erows, deg, hist, W1, W2, Wt1, Wt2);
    scan_phase12<<<N_SBLKS, SCAN_BLK, 0, stream>>>(deg, bsum, boff, rowptr, done);
    scan_phase3<<<N_SBLKS, SCAN_BLK, 0, stream>>>(deg, boff, rowptr);

    // --- edge partition into CSR order ---
    bucket_scan<<<N_BKT, 256, 0, stream>>>(hist, rowptr, off);
    partition<<<N_TILES, 256, 0, stream>>>(erows, ecols, evals, off, etmp);
    bucket_reorder<<<N_BKT, 256, 0, stream>>>(rowptr, etmp, epack);

    // --- Layer 1 GEMM: g1 = x @ W1 (f16) ---
    gemm_mfma<128, true><<<(N_NODES + 63) / 64, 256, 0, stream>>>(x, Wt1, g1, N_NODES);

    // --- FUSED Layer1-aggregate + Layer2 GEMM: g2 = relu(A_sp@g1) @ W2 ---
    spmm_gemm_fused<<<(N_NODES + 63) / 64, 512, 0, stream>>>(
        rowptr, (const long long*)epack, g1, Wt2, g2, N_NODES);

    // --- Layer 2 aggregate: agg2 = A_sp @ g2 ---
    spmm_csr_h<64, false><<<(N_NODES + 31) / 32, 256, 0, stream>>>(
        rowptr, (const long long*)epack, g2, agg2, N_NODES);

    // --- Decode ---
    decode_dot<<<((N_PAIRS + 1) / 2 * 8 + 255) / 256, 256, 0, stream>>>(
        agg2, pairs, out, N_PAIRS);
}